// Round 2
// baseline (1548.637 us; speedup 1.0000x reference)
//
#include <hip/hip_runtime.h>

#define BB 16384
#define SS 50
#define DD 256
#define HH 128
#define XP 260   // LDS row pitch in floats: 260*4=1040 B, 16B-aligned, breaks pow2 bank stride

typedef __attribute__((ext_vector_type(8))) __bf16 bf16x8;
typedef __attribute__((ext_vector_type(4))) float f32x4;

// ws prep: W1 [256][128] fp32 -> W1^T [128][256] bf16 (B-operand friendly: n-major, k contiguous)
__global__ __launch_bounds__(256) void prep_w1(const float* __restrict__ W1,
                                               __bf16* __restrict__ w1t) {
    int idx = blockIdx.x * 256 + threadIdx.x;   // 32768 total
    int n = idx >> 8;     // 0..127
    int k = idx & 255;    // 0..255
    w1t[n * 256 + k] = (__bf16)W1[k * HH + n];
}

template <bool USE_WS>
__global__ __launch_bounds__(256, 3) void user_enc(
    const float* __restrict__ vecs,   // [B,S,D]
    const int*   __restrict__ lmask,  // [B,S]
    const float* __restrict__ pad,    // [D]
    const float* __restrict__ b1,     // [H2]
    const float* __restrict__ W2,     // [H2]
    const float* __restrict__ b2,     // [1]
    const __bf16* __restrict__ w1t,   // [H2][D] bf16 (if USE_WS)
    const float* __restrict__ W1f,    // [D][H2] fp32 (fallback)
    float* __restrict__ out)          // [B,D]
{
    __shared__ __align__(16) float xs[SS * XP];   // 52000 B; head reused for partials later
    __shared__ float s_alpha[SS];
    __shared__ int   s_mask[SS];
    __shared__ float s_psum[4];

    const int b    = blockIdx.x;
    const int t    = threadIdx.x;
    const int wid  = t >> 6;
    const int lane = t & 63;
    const int lo16 = lane & 15;
    const int q    = lane >> 4;

    if (t < SS) s_mask[t] = lmask[b * SS + t];
    __syncthreads();

    // ---- stage x into LDS (mask-select; wave-uniform branch: 64 lanes == one s-row) ----
    const float4* vrow = (const float4*)(vecs + (size_t)b * (SS * DD));
    const float4* pad4 = (const float4*)pad;
    for (int i = t; i < SS * (DD / 4); i += 256) {
        int s = i >> 6;      // 64 float4 per row
        int c = i & 63;
        float4 v;
        if (s_mask[s] != 0) v = vrow[i];      // skipped entirely for masked rows -> no HBM fetch
        else                v = pad4[c];      // L1-resident
        *(float4*)&xs[s * XP + c * 4] = v;
    }
    __syncthreads();

    // ---- A fragments for this wave's 16-row M-tile, converted to bf16 once ----
    bf16x8 afr[8];
    const int r = (wid << 4) + lo16;          // A row for this lane
    if (r < SS) {
        const float* arow = &xs[r * XP + q * 8];
        #pragma unroll
        for (int kk = 0; kk < 8; ++kk) {
            float4 vlo = *(const float4*)(arow + kk * 32);
            float4 vhi = *(const float4*)(arow + kk * 32 + 4);
            bf16x8 f;
            f[0] = (__bf16)vlo.x; f[1] = (__bf16)vlo.y;
            f[2] = (__bf16)vlo.z; f[3] = (__bf16)vlo.w;
            f[4] = (__bf16)vhi.x; f[5] = (__bf16)vhi.y;
            f[6] = (__bf16)vhi.z; f[7] = (__bf16)vhi.w;
            afr[kk] = f;
        }
    } else {
        #pragma unroll
        for (int kk = 0; kk < 8; ++kk) {
            bf16x8 f;
            #pragma unroll
            for (int j = 0; j < 8; ++j) f[j] = (__bf16)0.0f;
            afr[kk] = f;
        }
    }

    const float b2v = b2[0];
    float zacc[4] = {0.f, 0.f, 0.f, 0.f};

    #pragma unroll
    for (int nt = 0; nt < 8; ++nt) {
        const int c = (nt << 4) + lo16;       // output column (h index)
        f32x4 acc = {0.f, 0.f, 0.f, 0.f};
        #pragma unroll
        for (int kk = 0; kk < 8; ++kk) {
            bf16x8 bfr;
            if constexpr (USE_WS) {
                bfr = *(const bf16x8*)(w1t + c * 256 + kk * 32 + q * 8);
            } else {
                #pragma unroll
                for (int j = 0; j < 8; ++j)
                    bfr[j] = (__bf16)W1f[(kk * 32 + q * 8 + j) * HH + c];
            }
            acc = __builtin_amdgcn_mfma_f32_16x16x32_bf16(afr[kk], bfr, acc, 0, 0, 0);
        }
        const float b1c = b1[c];
        const float w2c = W2[c];
        #pragma unroll
        for (int i = 0; i < 4; ++i) {
            float y = acc[i] + b1c;                       // y for row (q*4+i) of tile, col c
            y = fminf(fmaxf(y, -15.f), 15.f);
            float ex = __expf(2.f * y);
            float th = (ex - 1.f) * __builtin_amdgcn_rcpf(ex + 1.f);   // tanh(y)
            zacc[i] += th * w2c;
        }
    }

    // ---- reduce z over the 16 columns held by each 16-lane group; write alpha numerators ----
    #pragma unroll
    for (int i = 0; i < 4; ++i) {
        float z = zacc[i];
        z += __shfl_xor(z, 1);
        z += __shfl_xor(z, 2);
        z += __shfl_xor(z, 4);
        z += __shfl_xor(z, 8);
        if (lo16 == 0) {
            int srow = (wid << 4) + (q << 2) + i;
            if (srow < SS) s_alpha[srow] = __expf(z + b2v);
        }
    }
    __syncthreads();

    // ---- weighted sum: thread owns 4 columns (lane*4), waves split s 4-way ----
    float4 acc4 = {0.f, 0.f, 0.f, 0.f};
    float psum = 0.f;
    for (int s = wid; s < SS; s += 4) {
        float a = s_alpha[s];
        float4 xv = *(const float4*)&xs[s * XP + lane * 4];
        acc4.x += a * xv.x;
        acc4.y += a * xv.y;
        acc4.z += a * xv.z;
        acc4.w += a * xv.w;
        psum += a;
    }
    __syncthreads();
    *(float4*)&xs[(wid * 64 + lane) * 4] = acc4;   // reuse xs rows 0-3 as partial buffer
    if (lane == 0) s_psum[wid] = psum;
    __syncthreads();

    if (t < 64) {
        float4 p0 = *(const float4*)&xs[(0 * 64 + t) * 4];
        float4 p1 = *(const float4*)&xs[(1 * 64 + t) * 4];
        float4 p2 = *(const float4*)&xs[(2 * 64 + t) * 4];
        float4 p3 = *(const float4*)&xs[(3 * 64 + t) * 4];
        float denom = s_psum[0] + s_psum[1] + s_psum[2] + s_psum[3] + 1e-8f;
        float inv = 1.0f / denom;
        float4 o;
        o.x = (p0.x + p1.x + p2.x + p3.x) * inv;
        o.y = (p0.y + p1.y + p2.y + p3.y) * inv;
        o.z = (p0.z + p1.z + p2.z + p3.z) * inv;
        o.w = (p0.w + p1.w + p2.w + p3.w) * inv;
        *(float4*)(out + (size_t)b * DD + t * 4) = o;
    }
}

extern "C" void kernel_launch(void* const* d_in, const int* in_sizes, int n_in,
                              void* d_out, int out_size, void* d_ws, size_t ws_size,
                              hipStream_t stream) {
    const float* vecs  = (const float*)d_in[0];
    const int*   lmask = (const int*)d_in[1];
    const float* pad   = (const float*)d_in[2];
    const float* W1    = (const float*)d_in[3];
    const float* b1    = (const float*)d_in[4];
    const float* W2    = (const float*)d_in[5];
    const float* b2    = (const float*)d_in[6];
    float* out = (float*)d_out;

    if (ws_size >= (size_t)(HH * DD * sizeof(__bf16))) {
        __bf16* w1t = (__bf16*)d_ws;
        prep_w1<<<dim3(HH * DD / 256), dim3(256), 0, stream>>>(W1, w1t);
        user_enc<true><<<dim3(BB), dim3(256), 0, stream>>>(vecs, lmask, pad, b1, W2, b2,
                                                           w1t, W1, out);
    } else {
        user_enc<false><<<dim3(BB), dim3(256), 0, stream>>>(vecs, lmask, pad, b1, W2, b2,
                                                            nullptr, W1, out);
    }
}

// Round 3
// 1419.868 us; speedup vs baseline: 1.0907x; 1.0907x over previous
//
#include <hip/hip_runtime.h>

#define BB 16384
#define SS 50
#define DD 256
#define HH 128

typedef __attribute__((ext_vector_type(8))) __bf16 bf16x8;
typedef __attribute__((ext_vector_type(4))) float f32x4;

// ws prep: W1 [256][128] fp32 -> W1^T [128][256] bf16 (B-operand: n-major, k contiguous)
__global__ __launch_bounds__(256) void prep_w1(const float* __restrict__ W1,
                                               __bf16* __restrict__ w1t) {
    int idx = blockIdx.x * 256 + threadIdx.x;   // 32768 total
    int n = idx >> 8;     // 0..127
    int k = idx & 255;    // 0..255
    w1t[n * 256 + k] = (__bf16)W1[k * HH + n];
}

template <bool USE_WS>
__global__ __launch_bounds__(256, 4) void user_enc(
    const float* __restrict__ vecs,   // [B,S,D]
    const int*   __restrict__ lmask,  // [B,S]
    const float* __restrict__ pad,    // [D]
    const float* __restrict__ b1,     // [H2]
    const float* __restrict__ W2,     // [H2]
    const float* __restrict__ b2,     // [1]
    const __bf16* __restrict__ w1t,   // [H2][D] bf16 (if USE_WS)
    const float* __restrict__ W1f,    // [D][H2] fp32 (fallback)
    float* __restrict__ out)          // [B,D]
{
    // Tiny LDS only: alpha/mask rows + cross-wave partials. ~4.6 KB -> occupancy
    // is VGPR/wave-bound, not LDS-bound (was 52.7 KB -> 3 blocks/CU).
    __shared__ float s_alpha[SS];
    __shared__ float s_m[SS];
    __shared__ __align__(16) float s_part[256 * 4];
    __shared__ float s_sum[4], s_pad[4];

    const int b    = blockIdx.x;
    const int t    = threadIdx.x;
    const int wid  = t >> 6;
    const int lane = t & 63;
    const int lo16 = lane & 15;
    const int q    = lane >> 4;
    const int r    = (wid << 4) + lo16;        // this lane's A row (s index)

    // ---- per-lane row mask (16 distinct addrs/wave, broadcast across q) ----
    bool act = false;
    if (r < SS) act = (lmask[b * SS + r] != 0);
    if (q == 0 && r < SS) s_m[r] = act ? 1.0f : 0.0f;

    // ---- A fragments straight from global: pad default, overwrite when active ----
    // Active lanes: 16 indep. 16B loads (4-lane q-groups form 128B contiguous
    // segments). Masked rows issue NO global x loads -> ~half fetch skipped.
    const float* vrowp = vecs + (size_t)b * (SS * DD) + (size_t)r * DD;
    bf16x8 afr[8];
    #pragma unroll
    for (int kk = 0; kk < 8; ++kk) {
        const float* src = pad + kk * 32 + q * 8;    // L1-broadcast, mask-independent
        float4 lo = *(const float4*)(src);
        float4 hi = *(const float4*)(src + 4);
        bf16x8 f;
        f[0] = (__bf16)lo.x; f[1] = (__bf16)lo.y; f[2] = (__bf16)lo.z; f[3] = (__bf16)lo.w;
        f[4] = (__bf16)hi.x; f[5] = (__bf16)hi.y; f[6] = (__bf16)hi.z; f[7] = (__bf16)hi.w;
        afr[kk] = f;
    }
    if (act) {
        #pragma unroll
        for (int kk = 0; kk < 8; ++kk) {
            const float* src = vrowp + kk * 32 + q * 8;
            float4 lo = *(const float4*)(src);
            float4 hi = *(const float4*)(src + 4);
            bf16x8 f;
            f[0] = (__bf16)lo.x; f[1] = (__bf16)lo.y; f[2] = (__bf16)lo.z; f[3] = (__bf16)lo.w;
            f[4] = (__bf16)hi.x; f[5] = (__bf16)hi.y; f[6] = (__bf16)hi.z; f[7] = (__bf16)hi.w;
            afr[kk] = f;
        }
    }

    // ---- GEMM (8 n-tiles x 8 k-steps) + fused tanh + W2 dot ----
    const float b2v = b2[0];
    float zacc[4] = {0.f, 0.f, 0.f, 0.f};

    #pragma unroll
    for (int nt = 0; nt < 8; ++nt) {
        const int c = (nt << 4) + lo16;       // output column (h index)
        f32x4 acc = {0.f, 0.f, 0.f, 0.f};
        #pragma unroll
        for (int kk = 0; kk < 8; ++kk) {
            bf16x8 bfr;
            if constexpr (USE_WS) {
                bfr = *(const bf16x8*)(w1t + c * 256 + kk * 32 + q * 8);  // L2-hot 64KB
            } else {
                #pragma unroll
                for (int j = 0; j < 8; ++j)
                    bfr[j] = (__bf16)W1f[(kk * 32 + q * 8 + j) * HH + c];
            }
            acc = __builtin_amdgcn_mfma_f32_16x16x32_bf16(afr[kk], bfr, acc, 0, 0, 0);
        }
        const float b1c = b1[c];
        const float w2c = W2[c];
        #pragma unroll
        for (int i = 0; i < 4; ++i) {
            float y = acc[i] + b1c;                       // row (16w + q*4+i), col c
            y = fminf(fmaxf(y, -15.f), 15.f);
            float ex = __expf(2.f * y);
            float th = (ex - 1.f) * __builtin_amdgcn_rcpf(ex + 1.f);   // tanh(y)
            zacc[i] += th * w2c;
        }
    }

    // ---- reduce z across the 16 columns per lane-group; alpha numerators to LDS ----
    #pragma unroll
    for (int i = 0; i < 4; ++i) {
        float z = zacc[i];
        z += __shfl_xor(z, 1);
        z += __shfl_xor(z, 2);
        z += __shfl_xor(z, 4);
        z += __shfl_xor(z, 8);
        if (lo16 == 0) {
            int srow = (wid << 4) + (q << 2) + i;
            if (srow < SS) s_alpha[srow] = __expf(z + b2v);
        }
    }
    __syncthreads();   // barrier #1 (only cross-wave handoff: alpha + mask)

    // ---- weighted sum: coalesced L2-hot re-read of active rows; masked rows
    //      folded analytically as (sum_masked alpha) * pad ----
    float4 acc4 = {0.f, 0.f, 0.f, 0.f};
    float asum = 0.f, apad = 0.f;
    const float* vb = vecs + (size_t)b * (SS * DD);
    for (int s = wid; s < SS; s += 4) {
        float a = s_alpha[s];
        asum += a;
        if (s_m[s] != 0.0f) {                  // wave-uniform branch: skip load
            float4 xv = *(const float4*)(vb + s * DD + lane * 4);
            acc4.x += a * xv.x;
            acc4.y += a * xv.y;
            acc4.z += a * xv.z;
            acc4.w += a * xv.w;
        } else {
            apad += a;
        }
    }
    *(float4*)&s_part[t * 4] = acc4;
    if (lane == 0) { s_sum[wid] = asum; s_pad[wid] = apad; }
    __syncthreads();   // barrier #2

    if (t < 64) {
        float4 p0 = *(const float4*)&s_part[(0 * 64 + t) * 4];
        float4 p1 = *(const float4*)&s_part[(1 * 64 + t) * 4];
        float4 p2 = *(const float4*)&s_part[(2 * 64 + t) * 4];
        float4 p3 = *(const float4*)&s_part[(3 * 64 + t) * 4];
        float denom = s_sum[0] + s_sum[1] + s_sum[2] + s_sum[3] + 1e-8f;
        float ptot  = s_pad[0] + s_pad[1] + s_pad[2] + s_pad[3];
        float inv = 1.0f / denom;
        float4 pd = *(const float4*)(pad + t * 4);
        float4 o;
        o.x = (p0.x + p1.x + p2.x + p3.x + ptot * pd.x) * inv;
        o.y = (p0.y + p1.y + p2.y + p3.y + ptot * pd.y) * inv;
        o.z = (p0.z + p1.z + p2.z + p3.z + ptot * pd.z) * inv;
        o.w = (p0.w + p1.w + p2.w + p3.w + ptot * pd.w) * inv;
        *(float4*)(out + (size_t)b * DD + t * 4) = o;
    }
}

extern "C" void kernel_launch(void* const* d_in, const int* in_sizes, int n_in,
                              void* d_out, int out_size, void* d_ws, size_t ws_size,
                              hipStream_t stream) {
    const float* vecs  = (const float*)d_in[0];
    const int*   lmask = (const int*)d_in[1];
    const float* pad   = (const float*)d_in[2];
    const float* W1    = (const float*)d_in[3];
    const float* b1    = (const float*)d_in[4];
    const float* W2    = (const float*)d_in[5];
    const float* b2    = (const float*)d_in[6];
    float* out = (float*)d_out;

    if (ws_size >= (size_t)(HH * DD * sizeof(__bf16))) {
        __bf16* w1t = (__bf16*)d_ws;
        prep_w1<<<dim3(HH * DD / 256), dim3(256), 0, stream>>>(W1, w1t);
        user_enc<true><<<dim3(BB), dim3(256), 0, stream>>>(vecs, lmask, pad, b1, W2, b2,
                                                           w1t, W1, out);
    } else {
        user_enc<false><<<dim3(BB), dim3(256), 0, stream>>>(vecs, lmask, pad, b1, W2, b2,
                                                            nullptr, W1, out);
    }
}